// Round 2
// baseline (304.541 us; speedup 1.0000x reference)
//
#include <hip/hip_runtime.h>
#include <hip/hip_bf16.h>

// GeneralConv: out[i[e]] += (group-wise 16x16 GEMV, weight slice k[e]) of input[j[e]], + bias.
// N=100000, E=2000000, C=64, K=27, G=4.
//
// Pipeline: fused prep (zero counts + bf16 weight repack + bf16 x convert),
// rank (fetch-add per edge) -> 3-phase multi-block scan -> fill (atomic-free
// CSR build), then node-parallel gather: zero atomics, v_dot2_f32_bf16.
//
// R2 change: gather inner loop is an explicit software pipeline over edge
// PAIRS: x-loads for pair t+1 issue before computing pair t (one full
// compute phase of flight time), jk indices prefetched two pairs ahead.
// Plain loads + named ping-pong buffers -> compiler inserts counted waits
// at first use (no vmcnt(0) drains, unlike R1 which serialized and
// regressed). Register budget ~60 fits 64-VGPR / 8-waves-per-EU.

#define KPOS 27
#define WPACK_UINTS (KPOS * 512)     // [k][q][gc][m] bf16-pairs: 13824 uints = 55296 B
#define SCAN_NB 256                   // blocks in multi-block scan

typedef unsigned u32x4 __attribute__((ext_vector_type(4)));

__device__ __forceinline__ unsigned packbf(float a, float b) {
    unsigned ua = (unsigned)__bfloat16_as_ushort(__float2bfloat16(a));
    unsigned ub = (unsigned)__bfloat16_as_ushort(__float2bfloat16(b));
    return ua | (ub << 16);
}

// acc += bf16lo(x)*bf16lo(w) + bf16hi(x)*bf16hi(w)  -- one VOP3P instruction
#define DOT2(A, X, W) asm("v_dot2_f32_bf16 %0, %1, %2, %0" : "+v"(A) : "v"(X), "v"(W))

// ---------- fallback (used only if ws too small) ----------
__global__ void init_out_kernel(float* __restrict__ out, const float* __restrict__ bias, int total) {
    int idx = blockIdx.x * blockDim.x + threadIdx.x;
    if (idx < total) out[idx] = bias[idx & 63];
}
__global__ void edge_kernel_rawW(const float* __restrict__ input, const int* __restrict__ ei,
                                 const int* __restrict__ ej, const int* __restrict__ ek,
                                 const float* __restrict__ weight, float* __restrict__ out, int n_edges) {
    const int lane = threadIdx.x & 63;
    const int g16 = lane & 48;
    const int d = lane & 15;
    int wave = (blockIdx.x * blockDim.x + threadIdx.x) >> 6;
    int n_waves = (gridDim.x * blockDim.x) >> 6;
    for (int e = wave; e < n_edges; e += n_waves) {
        int ie = ei[e], je = ej[e], ke = ek[e];
        float x = input[je * 64 + lane];
        float acc = 0.0f;
        #pragma unroll
        for (int c = 0; c < 16; ++c)
            acc += __shfl(x, g16 + c, 64) * weight[(g16 + c) * 432 + d * 27 + ke];
        atomicAdd(out + ie * 64 + lane, acc);
    }
}

// ---------- fused prep: zero counts, repack weights, convert x ----------
__global__ void prep_kernel(const float* __restrict__ input, const float* __restrict__ weight,
                            unsigned* __restrict__ xb, unsigned* __restrict__ wp,
                            int* __restrict__ cnt, int n_nodes, int nquads) {
    int t = blockIdx.x * blockDim.x + threadIdx.x;
    if (t < n_nodes) cnt[t] = 0;
    if (t < WPACK_UINTS) {
        int k  = t >> 9;
        int r  = t & 511;
        int q  = r >> 8;
        int r2 = r & 255;
        int gc = r2 >> 2;
        int m  = r2 & 3;
        int g = gc >> 4, d = gc & 15;
        int c = (q * 4 + m) * 2;
        int ic = g * 16 + c;
        float f0 = weight[ic * 432 + d * 27 + k];
        float f1 = weight[(ic + 1) * 432 + d * 27 + k];
        wp[t] = packbf(f0, f1);
    }
    if (t < nquads) {
        const float4* in4 = (const float4*)input;
        float4 a = in4[2 * t], b = in4[2 * t + 1];
        uint4 o;
        o.x = packbf(a.x, a.y);
        o.y = packbf(a.z, a.w);
        o.z = packbf(b.x, b.y);
        o.w = packbf(b.z, b.w);
        ((uint4*)xb)[t] = o;
    }
}

// ---------- sort pipeline ----------
__global__ void rank_kernel(const int* __restrict__ ei, int* __restrict__ cnt,
                            unsigned short* __restrict__ rank, int n_edges) {
    int e = blockIdx.x * blockDim.x + threadIdx.x;
    if (e < n_edges)
        rank[e] = (unsigned short)atomicAdd(&cnt[ei[e]], 1);
}

// phase A: per-block partial sums of cnt chunks
__global__ void scanA_kernel(const int* __restrict__ cnt, int* __restrict__ partial,
                             int n, int chunk) {
    __shared__ int red[256];
    int b = blockIdx.x;
    int lo = b * chunk, hi = min(lo + chunk, n);
    int s = 0;
    for (int v = lo + threadIdx.x; v < hi; v += 256) s += cnt[v];
    red[threadIdx.x] = s;
    __syncthreads();
    for (int d = 128; d > 0; d >>= 1) {
        if (threadIdx.x < d) red[threadIdx.x] += red[threadIdx.x + d];
        __syncthreads();
    }
    if (threadIdx.x == 0) partial[b] = red[0];
}

// phase B: single tiny block scans SCAN_NB partials (exclusive), writes off[n]=total
__global__ void scanB_kernel(int* __restrict__ partial, int* __restrict__ off, int n) {
    __shared__ int sums[SCAN_NB];
    int t = threadIdx.x;
    sums[t] = partial[t];
    __syncthreads();
    for (int d = 1; d < SCAN_NB; d <<= 1) {
        int val = (t >= d) ? sums[t - d] : 0;
        __syncthreads();
        sums[t] += val;
        __syncthreads();
    }
    partial[t] = (t == 0) ? 0 : sums[t - 1];   // exclusive
    if (t == SCAN_NB - 1) off[n] = sums[t];
}

// phase C: per-block exclusive scan of its chunk, offset by partial[b]
__global__ void scanC_kernel(const int* __restrict__ cnt, const int* __restrict__ partial,
                             int* __restrict__ off, int n, int chunk) {
    __shared__ int excl[256];
    int b = blockIdx.x;
    int lo = b * chunk, hi = min(lo + chunk, n);
    int per = (chunk + 255) >> 8;
    int tlo = lo + threadIdx.x * per;
    int thi = min(tlo + per, hi);
    int s = 0;
    for (int v = tlo; v < thi; ++v) s += cnt[v];
    excl[threadIdx.x] = s;
    __syncthreads();
    for (int d = 1; d < 256; d <<= 1) {
        int val = (threadIdx.x >= d) ? excl[threadIdx.x - d] : 0;
        __syncthreads();
        excl[threadIdx.x] += val;
        __syncthreads();
    }
    int run = partial[b] + ((threadIdx.x == 0) ? 0 : excl[threadIdx.x - 1]);
    for (int v = tlo; v < thi; ++v) { off[v] = run; run += cnt[v]; }
}

__global__ void fill_kernel(const int* __restrict__ ei, const int* __restrict__ ej,
                            const int* __restrict__ ek, const int* __restrict__ off,
                            const unsigned short* __restrict__ rank,
                            unsigned* __restrict__ jk, int n_edges) {
    int e = blockIdx.x * blockDim.x + threadIdx.x;
    if (e < n_edges)
        jk[off[ei[e]] + (int)rank[e]] = (unsigned)ej[e] | ((unsigned)ek[e] << 17);
}

// ---------- gather: one wave per node, software-pipelined edge pairs ----------
__launch_bounds__(1024, 8)
__global__ void gather_kernel(const unsigned* __restrict__ xb,
                              const unsigned* __restrict__ jk,
                              const int* __restrict__ off,
                              const unsigned* __restrict__ wp,
                              const float* __restrict__ bias,
                              float* __restrict__ out, int n) {
    __shared__ unsigned lds[WPACK_UINTS];
    for (int t = threadIdx.x; t < WPACK_UINTS / 4; t += blockDim.x)
        ((uint4*)lds)[t] = ((const uint4*)wp)[t];
    __syncthreads();

    const int lane = threadIdx.x & 63;
    const int g8   = (lane & 48) >> 1;   // group offset in uints (bf16 pairs)
    const float b  = bias[lane];
    const unsigned* wl = lds + (lane << 2);

    int wid = (blockIdx.x * blockDim.x + threadIdx.x) >> 6;
    int nw  = (gridDim.x * blockDim.x) >> 6;

// issue the 4 x-loads of one edge pair into named regs (compiler defers wait to use)
#define XISSUE(P0, P1, XA, XC, XB2, XD) do {                                     \
        const u32x4* xp0_ = (const u32x4*)(xb + (((P0) & 0x1FFFFu) << 5) + g8);  \
        const u32x4* xp1_ = (const u32x4*)(xb + (((P1) & 0x1FFFFu) << 5) + g8);  \
        XA  = xp0_[0]; XC = xp0_[1];                                             \
        XB2 = xp1_[0]; XD = xp1_[1];                                             \
    } while (0)

// consume one edge: 2 LDS b128 weight reads + 8 dot2
#define PAIR_EDGE(XA, XC, PV, AL, AH) do {                                       \
        const u32x4* wr_ = (const u32x4*)(wl + (((PV) >> 17) << 9));             \
        u32x4 wa_ = wr_[0], wb_ = wr_[64];                                       \
        DOT2(AL, XA[0], wa_[0]); DOT2(AH, XA[1], wa_[1]);                        \
        DOT2(AL, XA[2], wa_[2]); DOT2(AH, XA[3], wa_[3]);                        \
        DOT2(AL, XC[0], wb_[0]); DOT2(AH, XC[1], wb_[1]);                        \
        DOT2(AL, XC[2], wb_[2]); DOT2(AH, XC[3], wb_[3]);                        \
    } while (0)

    for (int v = wid; v < n; v += nw) {
        int e0 = off[v];
        int e1 = off[v + 1];
        int nE = e1 - e0;
        int P  = nE >> 1;            // full pairs
        float a0l = 0.0f, a0h = 0.0f, a1l = 0.0f, a1h = 0.0f;

        if (P > 0) {
            // prologue: pair0 indices + x into A; pair1 indices prefetched
            unsigned pc0 = jk[e0], pc1 = jk[e0 + 1];
            u32x4 Aa, Ac, Ab, Ad;
            XISSUE(pc0, pc1, Aa, Ac, Ab, Ad);
            unsigned pn0 = pc0, pn1 = pc1;
            if (P > 1) { pn0 = jk[e0 + 2]; pn1 = jk[e0 + 3]; }
            u32x4 Ba, Bc, Bb, Bd;

            int t = 0;
            for (; t + 2 <= P; t += 2) {
                // ---- half 1: current pair t in A ----
                unsigned pf0 = pn0, pf1 = pn1;
                if (t + 2 < P) { pf0 = jk[e0 + 2 * t + 4]; pf1 = jk[e0 + 2 * t + 5]; }
                XISSUE(pn0, pn1, Ba, Bc, Bb, Bd);        // x(t+1) in flight
                PAIR_EDGE(Aa, Ac, pc0, a0l, a0h);        // compute pair t
                PAIR_EDGE(Ab, Ad, pc1, a1l, a1h);
                pc0 = pn0; pc1 = pn1; pn0 = pf0; pn1 = pf1;
                // ---- half 2: current pair t+1 in B ----
                unsigned pg0 = pn0, pg1 = pn1;
                if (t + 3 < P) { pg0 = jk[e0 + 2 * t + 6]; pg1 = jk[e0 + 2 * t + 7]; }
                if (t + 2 < P) XISSUE(pn0, pn1, Aa, Ac, Ab, Ad);  // x(t+2) in flight
                PAIR_EDGE(Ba, Bc, pc0, a0l, a0h);        // compute pair t+1
                PAIR_EDGE(Bb, Bd, pc1, a1l, a1h);
                pc0 = pn0; pc1 = pn1; pn0 = pg0; pn1 = pg1;
            }
            if (t < P) {             // P odd: last pair sits in A
                PAIR_EDGE(Aa, Ac, pc0, a0l, a0h);
                PAIR_EDGE(Ab, Ad, pc1, a1l, a1h);
            }
        }

        if (nE & 1) {                // tail edge
            unsigned p_ = jk[e1 - 1];
            const u32x4* xr_ = (const u32x4*)(xb + ((p_ & 0x1FFFFu) << 5) + g8);
            u32x4 xa_ = xr_[0], xc_ = xr_[1];
            PAIR_EDGE(xa_, xc_, p_, a0l, a0h);
        }

        out[(v << 6) + lane] = (a0l + a0h) + (a1l + a1h) + b;
    }
#undef XISSUE
#undef PAIR_EDGE
}

static inline size_t al256(size_t x) { return (x + 255) & ~(size_t)255; }

extern "C" void kernel_launch(void* const* d_in, const int* in_sizes, int n_in,
                              void* d_out, int out_size, void* d_ws, size_t ws_size,
                              hipStream_t stream) {
    const float* input  = (const float*)d_in[0];
    const int*   ei     = (const int*)d_in[1];
    const int*   ej     = (const int*)d_in[2];
    const int*   ek     = (const int*)d_in[3];
    const float* weight = (const float*)d_in[5];
    const float* bias   = (const float*)d_in[6];

    const int n_edges = in_sizes[1];
    const int n_nodes = out_size / 64;

    // workspace layout
    size_t off_o  = 0;
    size_t off_s  = al256((size_t)(n_nodes + 1) * 4);
    size_t cnt_o  = off_o + off_s;
    size_t cnt_s  = al256((size_t)n_nodes * 4);
    size_t par_o  = cnt_o + cnt_s;
    size_t par_s  = al256((size_t)SCAN_NB * 4);
    size_t rank_o = par_o + par_s;
    size_t rank_s = al256((size_t)n_edges * 2);
    size_t jk_o   = rank_o + rank_s;
    size_t jk_s   = al256((size_t)n_edges * 4);
    size_t wp_o   = jk_o + jk_s;
    size_t wp_s   = al256((size_t)WPACK_UINTS * 4);
    size_t xb_o   = wp_o + wp_s;
    size_t xb_s   = al256((size_t)n_nodes * 64 * 2);
    size_t need   = xb_o + xb_s;

    if (ws_size < need) {
        int blocks = (out_size + 255) / 256;
        hipLaunchKernelGGL(init_out_kernel, dim3(blocks), dim3(256), 0, stream,
                           (float*)d_out, bias, out_size);
        hipLaunchKernelGGL(edge_kernel_rawW, dim3(2048), dim3(256), 0, stream,
                           input, ei, ej, ek, weight, (float*)d_out, n_edges);
        return;
    }

    char* ws = (char*)d_ws;
    int*            off  = (int*)(ws + off_o);
    int*            cnt  = (int*)(ws + cnt_o);
    int*            par  = (int*)(ws + par_o);
    unsigned short* rank = (unsigned short*)(ws + rank_o);
    unsigned*       jk   = (unsigned*)(ws + jk_o);
    unsigned*       wp   = (unsigned*)(ws + wp_o);
    unsigned*       xb   = (unsigned*)(ws + xb_o);

    const int eb = (n_edges + 255) / 256;
    const int nquads = n_nodes * 8;
    const int prep_range = max(nquads, max(n_nodes, WPACK_UINTS));
    const int chunk = (n_nodes + SCAN_NB - 1) / SCAN_NB;

    // 1) fused prep: zero counts + repack weights + convert x
    hipLaunchKernelGGL(prep_kernel, dim3((prep_range + 255) / 256), dim3(256), 0, stream,
                       input, weight, xb, wp, cnt, n_nodes, nquads);
    // 2) counting sort -> CSR (atomic-free fill)
    hipLaunchKernelGGL(rank_kernel, dim3(eb), dim3(256), 0, stream, ei, cnt, rank, n_edges);
    hipLaunchKernelGGL(scanA_kernel, dim3(SCAN_NB), dim3(256), 0, stream, cnt, par, n_nodes, chunk);
    hipLaunchKernelGGL(scanB_kernel, dim3(1), dim3(SCAN_NB), 0, stream, par, off, n_nodes);
    hipLaunchKernelGGL(scanC_kernel, dim3(SCAN_NB), dim3(256), 0, stream, cnt, par, off, n_nodes, chunk);
    hipLaunchKernelGGL(fill_kernel, dim3(eb), dim3(256), 0, stream, ei, ej, ek, off, rank, jk, n_edges);

    // 3) gather-accumulate, one wave per node, no atomics
    hipLaunchKernelGGL(gather_kernel, dim3(512), dim3(1024), 0, stream,
                       xb, jk, off, wp, bias, (float*)d_out, n_nodes);
}

// Round 4
// 299.716 us; speedup vs baseline: 1.0161x; 1.0161x over previous
//
#include <hip/hip_runtime.h>
#include <hip/hip_bf16.h>

// GeneralConv: out[i[e]] += (group-wise 16x16 GEMV, weight slice k[e]) of input[j[e]], + bias.
// N=100000, E=2000000, C=64, K=27, G=4.
//
// Pipeline: fused prep (zero counts + bias-init out + bf16 weight repack + bf16 x
// convert), rank -> 3-phase scan -> fill (atomic-free CSR build, 8B records),
// then EDGE-WINDOW gather: each wave streams a fixed contiguous window of
// ~248 sorted edges. No off[] reads, no per-node pointer chains, perfect
// load balance. Node boundaries detected by scalar compare of the record's
// i field. R4 fix: ALL flushes are atomicAdd (bias pre-added by prep) --
// correctness no longer depends on interior/boundary classification: a
// missed or spurious boundary just splits a node's sum into two adds.
// Inner math identical to the best-measured R0 structure (4-edge batch,
// 8 x-loads issued up front, per-edge LDS weights, dot2).

#define KPOS 27
#define WPACK_UINTS (KPOS * 512)     // [k][q][gc][m] bf16-pairs: 13824 uints = 55296 B
#define SCAN_NB 256                   // blocks in multi-block scan

typedef unsigned u32x4 __attribute__((ext_vector_type(4)));

__device__ __forceinline__ unsigned packbf(float a, float b) {
    unsigned ua = (unsigned)__bfloat16_as_ushort(__float2bfloat16(a));
    unsigned ub = (unsigned)__bfloat16_as_ushort(__float2bfloat16(b));
    return ua | (ub << 16);
}

// acc += bf16lo(x)*bf16lo(w) + bf16hi(x)*bf16hi(w)  -- one VOP3P instruction
#define DOT2(A, X, W) asm("v_dot2_f32_bf16 %0, %1, %2, %0" : "+v"(A) : "v"(X), "v"(W))

// ---------- fallback (used only if ws too small) ----------
__global__ void init_out_kernel(float* __restrict__ out, const float* __restrict__ bias, int total) {
    int idx = blockIdx.x * blockDim.x + threadIdx.x;
    if (idx < total) out[idx] = bias[idx & 63];
}
__global__ void edge_kernel_rawW(const float* __restrict__ input, const int* __restrict__ ei,
                                 const int* __restrict__ ej, const int* __restrict__ ek,
                                 const float* __restrict__ weight, float* __restrict__ out, int n_edges) {
    const int lane = threadIdx.x & 63;
    const int g16 = lane & 48;
    const int d = lane & 15;
    int wave = (blockIdx.x * blockDim.x + threadIdx.x) >> 6;
    int n_waves = (gridDim.x * blockDim.x) >> 6;
    for (int e = wave; e < n_edges; e += n_waves) {
        int ie = ei[e], je = ej[e], ke = ek[e];
        float x = input[je * 64 + lane];
        float acc = 0.0f;
        #pragma unroll
        for (int c = 0; c < 16; ++c)
            acc += __shfl(x, g16 + c, 64) * weight[(g16 + c) * 432 + d * 27 + ke];
        atomicAdd(out + ie * 64 + lane, acc);
    }
}

// ---------- fused prep: zero counts, bias-init out, repack weights, convert x ----------
__global__ void prep_kernel(const float* __restrict__ input, const float* __restrict__ weight,
                            const float* __restrict__ bias, float* __restrict__ out,
                            unsigned* __restrict__ xb, unsigned* __restrict__ wp,
                            int* __restrict__ cnt, int n_nodes, int nquads, int nout4) {
    int t = blockIdx.x * blockDim.x + threadIdx.x;
    if (t < n_nodes) cnt[t] = 0;
    if (t < WPACK_UINTS) {
        int k  = t >> 9;
        int r  = t & 511;
        int q  = r >> 8;
        int r2 = r & 255;
        int gc = r2 >> 2;
        int m  = r2 & 3;
        int g = gc >> 4, d = gc & 15;
        int c = (q * 4 + m) * 2;
        int ic = g * 16 + c;
        float f0 = weight[ic * 432 + d * 27 + k];
        float f1 = weight[(ic + 1) * 432 + d * 27 + k];
        wp[t] = packbf(f0, f1);
    }
    if (t < nquads) {
        const float4* in4 = (const float4*)input;
        float4 a = in4[2 * t], b = in4[2 * t + 1];
        uint4 o;
        o.x = packbf(a.x, a.y);
        o.y = packbf(a.z, a.w);
        o.z = packbf(b.x, b.y);
        o.w = packbf(b.z, b.w);
        ((uint4*)xb)[t] = o;
    }
    if (t < nout4) {
        ((float4*)out)[t] = ((const float4*)bias)[t & 15];
    }
}

// ---------- sort pipeline ----------
__global__ void rank_kernel(const int* __restrict__ ei, int* __restrict__ cnt,
                            unsigned short* __restrict__ rank, int n_edges) {
    int e = blockIdx.x * blockDim.x + threadIdx.x;
    if (e < n_edges)
        rank[e] = (unsigned short)atomicAdd(&cnt[ei[e]], 1);
}

// phase A: per-block partial sums of cnt chunks
__global__ void scanA_kernel(const int* __restrict__ cnt, int* __restrict__ partial,
                             int n, int chunk) {
    __shared__ int red[256];
    int b = blockIdx.x;
    int lo = b * chunk, hi = min(lo + chunk, n);
    int s = 0;
    for (int v = lo + threadIdx.x; v < hi; v += 256) s += cnt[v];
    red[threadIdx.x] = s;
    __syncthreads();
    for (int d = 128; d > 0; d >>= 1) {
        if (threadIdx.x < d) red[threadIdx.x] += red[threadIdx.x + d];
        __syncthreads();
    }
    if (threadIdx.x == 0) partial[b] = red[0];
}

// phase B: single tiny block scans SCAN_NB partials (exclusive), writes off[n]=total
__global__ void scanB_kernel(int* __restrict__ partial, int* __restrict__ off, int n) {
    __shared__ int sums[SCAN_NB];
    int t = threadIdx.x;
    sums[t] = partial[t];
    __syncthreads();
    for (int d = 1; d < SCAN_NB; d <<= 1) {
        int val = (t >= d) ? sums[t - d] : 0;
        __syncthreads();
        sums[t] += val;
        __syncthreads();
    }
    partial[t] = (t == 0) ? 0 : sums[t - 1];   // exclusive
    if (t == SCAN_NB - 1) off[n] = sums[t];
}

// phase C: per-block exclusive scan of its chunk, offset by partial[b]
__global__ void scanC_kernel(const int* __restrict__ cnt, const int* __restrict__ partial,
                             int* __restrict__ off, int n, int chunk) {
    __shared__ int excl[256];
    int b = blockIdx.x;
    int lo = b * chunk, hi = min(lo + chunk, n);
    int per = (chunk + 255) >> 8;
    int tlo = lo + threadIdx.x * per;
    int thi = min(tlo + per, hi);
    int s = 0;
    for (int v = tlo; v < thi; ++v) s += cnt[v];
    excl[threadIdx.x] = s;
    __syncthreads();
    for (int d = 1; d < 256; d <<= 1) {
        int val = (threadIdx.x >= d) ? excl[threadIdx.x - d] : 0;
        __syncthreads();
        excl[threadIdx.x] += val;
        __syncthreads();
    }
    int run = partial[b] + ((threadIdx.x == 0) ? 0 : excl[threadIdx.x - 1]);
    for (int v = tlo; v < thi; ++v) { off[v] = run; run += cnt[v]; }
}

// fill: 8-byte record per edge: {j | k<<17, i}
__global__ void fill_kernel(const int* __restrict__ ei, const int* __restrict__ ej,
                            const int* __restrict__ ek, const int* __restrict__ off,
                            const unsigned short* __restrict__ rank,
                            uint2* __restrict__ recs, int n_edges) {
    int e = blockIdx.x * blockDim.x + threadIdx.x;
    if (e < n_edges) {
        int ie = ei[e];
        uint2 r;
        r.x = (unsigned)ej[e] | ((unsigned)ek[e] << 17);
        r.y = (unsigned)ie;
        recs[off[ie] + (int)rank[e]] = r;
    }
}

// ---------- gather: edge-window streaming, all-atomic flushes ----------
__launch_bounds__(1024, 8)
__global__ void gather_kernel(const unsigned* __restrict__ xb,
                              const uint2* __restrict__ recs,
                              const unsigned* __restrict__ wp,
                              float* __restrict__ out, int n_edges) {
    __shared__ unsigned lds[WPACK_UINTS];
    for (int t = threadIdx.x; t < WPACK_UINTS / 4; t += blockDim.x)
        ((uint4*)lds)[t] = ((const uint4*)wp)[t];
    __syncthreads();

    const int lane = threadIdx.x & 63;
    const int g8   = (lane & 48) >> 1;   // group offset in uints (bf16 pairs)
    const unsigned* wl = lds + (lane << 2);

    int wid = (blockIdx.x * blockDim.x + threadIdx.x) >> 6;
    int nw  = (gridDim.x * blockDim.x) >> 6;
    int epw = (((n_edges + nw - 1) / nw) + 7) & ~7;   // edges per wave, mult of 8
    int e    = wid * epw;
    int eend = min(e + epw, n_edges);
    if (e >= eend) return;

    int  cur = -1;           // current node id (wave-uniform)
    float a0l = 0.0f, a0h = 0.0f, a1l = 0.0f, a1h = 0.0f;

#define FLUSH_CHANGE() do {                                                   \
        if (cur >= 0) {                                                       \
            float s_ = (a0l + a0h) + (a1l + a1h);                             \
            atomicAdd(out + (cur << 6) + lane, s_);                           \
            a0l = a0h = a1l = a1h = 0.0f;                                     \
        }                                                                     \
    } while (0)

#define EDGE_BODY(P, AL, AH)                                                \
        do {                                                                \
            unsigned p_ = (P);                                              \
            const u32x4* wr = (const u32x4*)(wl + ((p_ >> 17) << 9));       \
            const u32x4* xr = (const u32x4*)(xb + ((p_ & 0x1FFFFu) << 5) + g8); \
            u32x4 xa = xr[0], xc = xr[1];                                   \
            u32x4 wa = wr[0], wb = wr[64];                                  \
            DOT2(AL, xa[0], wa[0]); DOT2(AH, xa[1], wa[1]);                 \
            DOT2(AL, xa[2], wa[2]); DOT2(AH, xa[3], wa[3]);                 \
            DOT2(AL, xc[0], wb[0]); DOT2(AH, xc[1], wb[1]);                 \
            DOT2(AL, xc[2], wb[2]); DOT2(AH, xc[3], wb[3]);                 \
        } while (0)

    // main loop: 4-edge batches, 8 x-loads issued up front (R0 structure)
    for (; e + 4 <= eend; e += 4) {
        const uint4* rc = (const uint4*)(recs + e);
        uint4 r01 = rc[0], r23 = rc[1];
        const u32x4* x0 = (const u32x4*)(xb + ((r01.x & 0x1FFFFu) << 5) + g8);
        const u32x4* x1 = (const u32x4*)(xb + ((r01.z & 0x1FFFFu) << 5) + g8);
        const u32x4* x2 = (const u32x4*)(xb + ((r23.x & 0x1FFFFu) << 5) + g8);
        const u32x4* x3 = (const u32x4*)(xb + ((r23.z & 0x1FFFFu) << 5) + g8);
        u32x4 xa0 = x0[0], xc0 = x0[1];
        u32x4 xa1 = x1[0], xc1 = x1[1];
        u32x4 xa2 = x2[0], xc2 = x2[1];
        u32x4 xa3 = x3[0], xc3 = x3[1];
        int i0 = __builtin_amdgcn_readfirstlane((int)r01.y);
        int i1 = __builtin_amdgcn_readfirstlane((int)r01.w);
        int i2 = __builtin_amdgcn_readfirstlane((int)r23.y);
        int i3 = __builtin_amdgcn_readfirstlane((int)r23.w);

        if (i0 != cur) { FLUSH_CHANGE(); cur = i0; }
        {
            const u32x4* wr = (const u32x4*)(wl + ((r01.x >> 17) << 9));
            u32x4 wa = wr[0], wb2 = wr[64];
            DOT2(a0l, xa0[0], wa[0]); DOT2(a0h, xa0[1], wa[1]);
            DOT2(a0l, xa0[2], wa[2]); DOT2(a0h, xa0[3], wa[3]);
            DOT2(a0l, xc0[0], wb2[0]); DOT2(a0h, xc0[1], wb2[1]);
            DOT2(a0l, xc0[2], wb2[2]); DOT2(a0h, xc0[3], wb2[3]);
        }
        if (i1 != cur) { FLUSH_CHANGE(); cur = i1; }
        {
            const u32x4* wr = (const u32x4*)(wl + ((r01.z >> 17) << 9));
            u32x4 wa = wr[0], wb2 = wr[64];
            DOT2(a1l, xa1[0], wa[0]); DOT2(a1h, xa1[1], wa[1]);
            DOT2(a1l, xa1[2], wa[2]); DOT2(a1h, xa1[3], wa[3]);
            DOT2(a1l, xc1[0], wb2[0]); DOT2(a1h, xc1[1], wb2[1]);
            DOT2(a1l, xc1[2], wb2[2]); DOT2(a1h, xc1[3], wb2[3]);
        }
        if (i2 != cur) { FLUSH_CHANGE(); cur = i2; }
        {
            const u32x4* wr = (const u32x4*)(wl + ((r23.x >> 17) << 9));
            u32x4 wa = wr[0], wb2 = wr[64];
            DOT2(a0l, xa2[0], wa[0]); DOT2(a0h, xa2[1], wa[1]);
            DOT2(a0l, xa2[2], wa[2]); DOT2(a0h, xa2[3], wa[3]);
            DOT2(a0l, xc2[0], wb2[0]); DOT2(a0h, xc2[1], wb2[1]);
            DOT2(a0l, xc2[2], wb2[2]); DOT2(a0h, xc2[3], wb2[3]);
        }
        if (i3 != cur) { FLUSH_CHANGE(); cur = i3; }
        {
            const u32x4* wr = (const u32x4*)(wl + ((r23.z >> 17) << 9));
            u32x4 wa = wr[0], wb2 = wr[64];
            DOT2(a1l, xa3[0], wa[0]); DOT2(a1h, xa3[1], wa[1]);
            DOT2(a1l, xa3[2], wa[2]); DOT2(a1h, xa3[3], wa[3]);
            DOT2(a1l, xc3[0], wb2[0]); DOT2(a1h, xc3[1], wb2[1]);
            DOT2(a1l, xc3[2], wb2[2]); DOT2(a1h, xc3[3], wb2[3]);
        }
    }

    // tail edges
    for (; e < eend; ++e) {
        uint2 r = recs[e];
        int ri = __builtin_amdgcn_readfirstlane((int)r.y);
        if (ri != cur) { FLUSH_CHANGE(); cur = ri; }
        EDGE_BODY(r.x, a0l, a0h);
    }

    // final run of the window
    FLUSH_CHANGE();
#undef EDGE_BODY
#undef FLUSH_CHANGE
}

static inline size_t al256(size_t x) { return (x + 255) & ~(size_t)255; }

extern "C" void kernel_launch(void* const* d_in, const int* in_sizes, int n_in,
                              void* d_out, int out_size, void* d_ws, size_t ws_size,
                              hipStream_t stream) {
    const float* input  = (const float*)d_in[0];
    const int*   ei     = (const int*)d_in[1];
    const int*   ej     = (const int*)d_in[2];
    const int*   ek     = (const int*)d_in[3];
    const float* weight = (const float*)d_in[5];
    const float* bias   = (const float*)d_in[6];

    const int n_edges = in_sizes[1];
    const int n_nodes = out_size / 64;

    // workspace layout
    size_t off_o  = 0;
    size_t off_s  = al256((size_t)(n_nodes + 1) * 4);
    size_t cnt_o  = off_o + off_s;
    size_t cnt_s  = al256((size_t)n_nodes * 4);
    size_t par_o  = cnt_o + cnt_s;
    size_t par_s  = al256((size_t)SCAN_NB * 4);
    size_t rank_o = par_o + par_s;
    size_t rank_s = al256((size_t)n_edges * 2);
    size_t rec_o  = rank_o + rank_s;
    size_t rec_s  = al256((size_t)n_edges * 8);
    size_t wp_o   = rec_o + rec_s;
    size_t wp_s   = al256((size_t)WPACK_UINTS * 4);
    size_t xb_o   = wp_o + wp_s;
    size_t xb_s   = al256((size_t)n_nodes * 64 * 2);
    size_t need   = xb_o + xb_s;

    if (ws_size < need) {
        int blocks = (out_size + 255) / 256;
        hipLaunchKernelGGL(init_out_kernel, dim3(blocks), dim3(256), 0, stream,
                           (float*)d_out, bias, out_size);
        hipLaunchKernelGGL(edge_kernel_rawW, dim3(2048), dim3(256), 0, stream,
                           input, ei, ej, ek, weight, (float*)d_out, n_edges);
        return;
    }

    char* ws = (char*)d_ws;
    int*            off  = (int*)(ws + off_o);
    int*            cnt  = (int*)(ws + cnt_o);
    int*            par  = (int*)(ws + par_o);
    unsigned short* rank = (unsigned short*)(ws + rank_o);
    uint2*          recs = (uint2*)(ws + rec_o);
    unsigned*       wp   = (unsigned*)(ws + wp_o);
    unsigned*       xb   = (unsigned*)(ws + xb_o);

    const int eb = (n_edges + 255) / 256;
    const int nquads = n_nodes * 8;
    const int nout4  = n_nodes * 16;
    const int prep_range = max(max(nquads, nout4), max(n_nodes, WPACK_UINTS));
    const int chunk = (n_nodes + SCAN_NB - 1) / SCAN_NB;

    // 1) fused prep: zero counts + bias-init out + repack weights + convert x
    hipLaunchKernelGGL(prep_kernel, dim3((prep_range + 255) / 256), dim3(256), 0, stream,
                       input, weight, bias, (float*)d_out, xb, wp, cnt,
                       n_nodes, nquads, nout4);
    // 2) counting sort -> CSR records (atomic-free fill)
    hipLaunchKernelGGL(rank_kernel, dim3(eb), dim3(256), 0, stream, ei, cnt, rank, n_edges);
    hipLaunchKernelGGL(scanA_kernel, dim3(SCAN_NB), dim3(256), 0, stream, cnt, par, n_nodes, chunk);
    hipLaunchKernelGGL(scanB_kernel, dim3(1), dim3(SCAN_NB), 0, stream, par, off, n_nodes);
    hipLaunchKernelGGL(scanC_kernel, dim3(SCAN_NB), dim3(256), 0, stream, cnt, par, off, n_nodes, chunk);
    hipLaunchKernelGGL(fill_kernel, dim3(eb), dim3(256), 0, stream, ei, ej, ek, off, rank, recs, n_edges);

    // 3) edge-window gather, all-atomic flushes
    hipLaunchKernelGGL(gather_kernel, dim3(512), dim3(1024), 0, stream,
                       xb, recs, wp, (float*)d_out, n_edges);
}

// Round 5
// 294.210 us; speedup vs baseline: 1.0351x; 1.0187x over previous
//
#include <hip/hip_runtime.h>
#include <hip/hip_bf16.h>

// GeneralConv: out[i[e]] += (group-wise 16x16 GEMV, weight slice k[e]) of input[j[e]], + bias.
// N=100000, E=2000000, C=64, K=27, G=4.
//
// Pipeline: fused prep (zero counts + bias-init out + bf16 weight repack + bf16 x
// convert), rank -> 3-phase scan -> fill (CSR build, 8B records), then gather.
//
// R5 change: HALF-WAVE PER EDGE in the gather. Bandwidth audit showed the
// old one-wave-per-edge scheme moved 2KB/edge through the L1 return path
// (64 lanes x 32B, 16-way broadcast redundancy) -- the binding constraint
// (~104us), above the LDS weight floor (~78us). Now lanes 0-31 process edge
// e and lanes 32-63 edge e+1; each lane computes TWO output channels (d,
// d+8) of its group from the same 32B of x -> x return halves to 1KB/edge.
// LDS weight traffic, dot2 count, conflict profile unchanged. Node tracking
// is per-lane (cur in VGPR, predicated atomic flushes under __any); all
// flushes atomicAdd (bias pre-added by prep), so correctness does not
// depend on boundary classification.

#define KPOS 27
#define WPACK_UINTS (KPOS * 512)     // [k][q][gc][m] bf16-pairs: 13824 uints = 55296 B
#define SCAN_NB 256                   // blocks in multi-block scan

typedef unsigned u32x4 __attribute__((ext_vector_type(4)));

__device__ __forceinline__ unsigned packbf(float a, float b) {
    unsigned ua = (unsigned)__bfloat16_as_ushort(__float2bfloat16(a));
    unsigned ub = (unsigned)__bfloat16_as_ushort(__float2bfloat16(b));
    return ua | (ub << 16);
}

// acc += bf16lo(x)*bf16lo(w) + bf16hi(x)*bf16hi(w)  -- one VOP3P instruction
#define DOT2(A, X, W) asm("v_dot2_f32_bf16 %0, %1, %2, %0" : "+v"(A) : "v"(X), "v"(W))

// ---------- fallback (used only if ws too small) ----------
__global__ void init_out_kernel(float* __restrict__ out, const float* __restrict__ bias, int total) {
    int idx = blockIdx.x * blockDim.x + threadIdx.x;
    if (idx < total) out[idx] = bias[idx & 63];
}
__global__ void edge_kernel_rawW(const float* __restrict__ input, const int* __restrict__ ei,
                                 const int* __restrict__ ej, const int* __restrict__ ek,
                                 const float* __restrict__ weight, float* __restrict__ out, int n_edges) {
    const int lane = threadIdx.x & 63;
    const int g16 = lane & 48;
    const int d = lane & 15;
    int wave = (blockIdx.x * blockDim.x + threadIdx.x) >> 6;
    int n_waves = (gridDim.x * blockDim.x) >> 6;
    for (int e = wave; e < n_edges; e += n_waves) {
        int ie = ei[e], je = ej[e], ke = ek[e];
        float x = input[je * 64 + lane];
        float acc = 0.0f;
        #pragma unroll
        for (int c = 0; c < 16; ++c)
            acc += __shfl(x, g16 + c, 64) * weight[(g16 + c) * 432 + d * 27 + ke];
        atomicAdd(out + ie * 64 + lane, acc);
    }
}

// ---------- fused prep: zero counts, bias-init out, repack weights, convert x ----------
__global__ void prep_kernel(const float* __restrict__ input, const float* __restrict__ weight,
                            const float* __restrict__ bias, float* __restrict__ out,
                            unsigned* __restrict__ xb, unsigned* __restrict__ wp,
                            int* __restrict__ cnt, int n_nodes, int nquads, int nout4) {
    int t = blockIdx.x * blockDim.x + threadIdx.x;
    if (t < n_nodes) cnt[t] = 0;
    if (t < WPACK_UINTS) {
        int k  = t >> 9;
        int r  = t & 511;
        int q  = r >> 8;
        int r2 = r & 255;
        int gc = r2 >> 2;
        int m  = r2 & 3;
        int g = gc >> 4, d = gc & 15;
        int c = (q * 4 + m) * 2;
        int ic = g * 16 + c;
        float f0 = weight[ic * 432 + d * 27 + k];
        float f1 = weight[(ic + 1) * 432 + d * 27 + k];
        wp[t] = packbf(f0, f1);
    }
    if (t < nquads) {
        const float4* in4 = (const float4*)input;
        float4 a = in4[2 * t], b = in4[2 * t + 1];
        uint4 o;
        o.x = packbf(a.x, a.y);
        o.y = packbf(a.z, a.w);
        o.z = packbf(b.x, b.y);
        o.w = packbf(b.z, b.w);
        ((uint4*)xb)[t] = o;
    }
    if (t < nout4) {
        ((float4*)out)[t] = ((const float4*)bias)[t & 15];
    }
}

// ---------- sort pipeline ----------
__global__ void rank_kernel(const int* __restrict__ ei, int* __restrict__ cnt,
                            unsigned short* __restrict__ rank, int n_edges) {
    int e = blockIdx.x * blockDim.x + threadIdx.x;
    if (e < n_edges)
        rank[e] = (unsigned short)atomicAdd(&cnt[ei[e]], 1);
}

// phase A: per-block partial sums of cnt chunks
__global__ void scanA_kernel(const int* __restrict__ cnt, int* __restrict__ partial,
                             int n, int chunk) {
    __shared__ int red[256];
    int b = blockIdx.x;
    int lo = b * chunk, hi = min(lo + chunk, n);
    int s = 0;
    for (int v = lo + threadIdx.x; v < hi; v += 256) s += cnt[v];
    red[threadIdx.x] = s;
    __syncthreads();
    for (int d = 128; d > 0; d >>= 1) {
        if (threadIdx.x < d) red[threadIdx.x] += red[threadIdx.x + d];
        __syncthreads();
    }
    if (threadIdx.x == 0) partial[b] = red[0];
}

// phase B: single tiny block scans SCAN_NB partials (exclusive), writes off[n]=total
__global__ void scanB_kernel(int* __restrict__ partial, int* __restrict__ off, int n) {
    __shared__ int sums[SCAN_NB];
    int t = threadIdx.x;
    sums[t] = partial[t];
    __syncthreads();
    for (int d = 1; d < SCAN_NB; d <<= 1) {
        int val = (t >= d) ? sums[t - d] : 0;
        __syncthreads();
        sums[t] += val;
        __syncthreads();
    }
    partial[t] = (t == 0) ? 0 : sums[t - 1];   // exclusive
    if (t == SCAN_NB - 1) off[n] = sums[t];
}

// phase C: per-block exclusive scan of its chunk, offset by partial[b]
__global__ void scanC_kernel(const int* __restrict__ cnt, const int* __restrict__ partial,
                             int* __restrict__ off, int n, int chunk) {
    __shared__ int excl[256];
    int b = blockIdx.x;
    int lo = b * chunk, hi = min(lo + chunk, n);
    int per = (chunk + 255) >> 8;
    int tlo = lo + threadIdx.x * per;
    int thi = min(tlo + per, hi);
    int s = 0;
    for (int v = tlo; v < thi; ++v) s += cnt[v];
    excl[threadIdx.x] = s;
    __syncthreads();
    for (int d = 1; d < 256; d <<= 1) {
        int val = (threadIdx.x >= d) ? excl[threadIdx.x - d] : 0;
        __syncthreads();
        excl[threadIdx.x] += val;
        __syncthreads();
    }
    int run = partial[b] + ((threadIdx.x == 0) ? 0 : excl[threadIdx.x - 1]);
    for (int v = tlo; v < thi; ++v) { off[v] = run; run += cnt[v]; }
}

// fill: 8-byte record per edge: {j | k<<17, i}
__global__ void fill_kernel(const int* __restrict__ ei, const int* __restrict__ ej,
                            const int* __restrict__ ek, const int* __restrict__ off,
                            const unsigned short* __restrict__ rank,
                            uint2* __restrict__ recs, int n_edges) {
    int e = blockIdx.x * blockDim.x + threadIdx.x;
    if (e < n_edges) {
        int ie = ei[e];
        uint2 r;
        r.x = (unsigned)ej[e] | ((unsigned)ek[e] << 17);
        r.y = (unsigned)ie;
        recs[off[ie] + (int)rank[e]] = r;
    }
}

// ---------- gather: half-wave per edge, 2 channels/lane, per-lane node tracking ----------
__launch_bounds__(1024, 8)
__global__ void gather_kernel(const unsigned* __restrict__ xb,
                              const uint2* __restrict__ recs,
                              const unsigned* __restrict__ wp,
                              float* __restrict__ out, int n_edges) {
    __shared__ unsigned lds[WPACK_UINTS];
    for (int t = threadIdx.x; t < WPACK_UINTS / 4; t += blockDim.x)
        ((uint4*)lds)[t] = ((const uint4*)wp)[t];
    __syncthreads();

    const int lane  = threadIdx.x & 63;
    const int half  = lane >> 5;             // 0: edges e, e+2 ; 1: edges e+1, e+3
    const int g     = (lane >> 3) & 3;       // group
    const int dp    = lane & 7;              // d base (second channel = dp+8)
    const int g8u   = g << 3;                // group offset within x row (uints)
    const int wbase = ((g << 4) + dp) << 2;  // gc0*4 (uints)
    const int och   = (g << 4) + dp;         // output channel base

    int wid = (blockIdx.x * blockDim.x + threadIdx.x) >> 6;
    int nw  = (gridDim.x * blockDim.x) >> 6;
    int epw = (((n_edges + nw - 1) / nw) + 3) & ~3;   // edges per wave, mult of 4
    int e    = wid * epw;
    int eend = min(e + epw, n_edges);
    if (e >= eend) return;

    const int elast = n_edges - 1;
    int cur = -1;                  // per-lane current node
    float a0l = 0.f, a0h = 0.f, a1l = 0.f, a1h = 0.f;

#define FLUSH_LANE() do {                                                     \
        atomicAdd(out + (cur << 6) + och,     a0l + a0h);                     \
        atomicAdd(out + (cur << 6) + och + 8, a1l + a1h);                     \
    } while (0)

#define EDGE_SET(RX, RY, XA, XC) do {                                         \
        int ri_ = (int)(RY);                                                  \
        if (__any(ri_ != cur)) {                                              \
            bool ch_ = (ri_ != cur);                                          \
            if (ch_) {                                                        \
                if (cur >= 0) FLUSH_LANE();                                   \
                cur = ri_;                                                    \
                a0l = a0h = a1l = a1h = 0.f;                                  \
            }                                                                 \
        }                                                                     \
        {                                                                     \
            const u32x4* wq_ = (const u32x4*)(lds + (((RX) >> 17) << 9) + wbase); \
            u32x4 w00 = wq_[0], w01 = wq_[64], w10 = wq_[8], w11 = wq_[72];   \
            DOT2(a0l, XA[0], w00[0]); DOT2(a0l, XA[1], w00[1]);               \
            DOT2(a0l, XA[2], w00[2]); DOT2(a0l, XA[3], w00[3]);               \
            DOT2(a0h, XC[0], w01[0]); DOT2(a0h, XC[1], w01[1]);               \
            DOT2(a0h, XC[2], w01[2]); DOT2(a0h, XC[3], w01[3]);               \
            DOT2(a1l, XA[0], w10[0]); DOT2(a1l, XA[1], w10[1]);               \
            DOT2(a1l, XA[2], w10[2]); DOT2(a1l, XA[3], w10[3]);               \
            DOT2(a1h, XC[0], w11[0]); DOT2(a1h, XC[1], w11[1]);               \
            DOT2(a1h, XC[2], w11[2]); DOT2(a1h, XC[3], w11[3]);               \
        }                                                                     \
    } while (0)

    for (; e < eend; e += 4) {
        int i0 = e + half, i1 = e + 2 + half;
        bool v0 = i0 < eend, v1 = i1 < eend;
        if (i0 > elast) i0 = elast;
        if (i1 > elast) i1 = elast;
        uint2 r0 = recs[i0], r1 = recs[i1];
        const u32x4* xp0 = (const u32x4*)(xb + ((r0.x & 0x1FFFFu) << 5) + g8u);
        const u32x4* xp1 = (const u32x4*)(xb + ((r1.x & 0x1FFFFu) << 5) + g8u);
        u32x4 xa0 = xp0[0], xc0 = xp0[1];
        u32x4 xa1 = xp1[0], xc1 = xp1[1];
        if (!v0) { xa0[0]=xa0[1]=xa0[2]=xa0[3]=0u; xc0[0]=xc0[1]=xc0[2]=xc0[3]=0u; }
        if (!v1) { xa1[0]=xa1[1]=xa1[2]=xa1[3]=0u; xc1[0]=xc1[1]=xc1[2]=xc1[3]=0u; }

        EDGE_SET(r0.x, r0.y, xa0, xc0);
        EDGE_SET(r1.x, r1.y, xa1, xc1);
    }

    if (cur >= 0) FLUSH_LANE();
#undef EDGE_SET
#undef FLUSH_LANE
}

static inline size_t al256(size_t x) { return (x + 255) & ~(size_t)255; }

extern "C" void kernel_launch(void* const* d_in, const int* in_sizes, int n_in,
                              void* d_out, int out_size, void* d_ws, size_t ws_size,
                              hipStream_t stream) {
    const float* input  = (const float*)d_in[0];
    const int*   ei     = (const int*)d_in[1];
    const int*   ej     = (const int*)d_in[2];
    const int*   ek     = (const int*)d_in[3];
    const float* weight = (const float*)d_in[5];
    const float* bias   = (const float*)d_in[6];

    const int n_edges = in_sizes[1];
    const int n_nodes = out_size / 64;

    // workspace layout
    size_t off_o  = 0;
    size_t off_s  = al256((size_t)(n_nodes + 1) * 4);
    size_t cnt_o  = off_o + off_s;
    size_t cnt_s  = al256((size_t)n_nodes * 4);
    size_t par_o  = cnt_o + cnt_s;
    size_t par_s  = al256((size_t)SCAN_NB * 4);
    size_t rank_o = par_o + par_s;
    size_t rank_s = al256((size_t)n_edges * 2);
    size_t rec_o  = rank_o + rank_s;
    size_t rec_s  = al256((size_t)n_edges * 8);
    size_t wp_o   = rec_o + rec_s;
    size_t wp_s   = al256((size_t)WPACK_UINTS * 4);
    size_t xb_o   = wp_o + wp_s;
    size_t xb_s   = al256((size_t)n_nodes * 64 * 2);
    size_t need   = xb_o + xb_s;

    if (ws_size < need) {
        int blocks = (out_size + 255) / 256;
        hipLaunchKernelGGL(init_out_kernel, dim3(blocks), dim3(256), 0, stream,
                           (float*)d_out, bias, out_size);
        hipLaunchKernelGGL(edge_kernel_rawW, dim3(2048), dim3(256), 0, stream,
                           input, ei, ej, ek, weight, (float*)d_out, n_edges);
        return;
    }

    char* ws = (char*)d_ws;
    int*            off  = (int*)(ws + off_o);
    int*            cnt  = (int*)(ws + cnt_o);
    int*            par  = (int*)(ws + par_o);
    unsigned short* rank = (unsigned short*)(ws + rank_o);
    uint2*          recs = (uint2*)(ws + rec_o);
    unsigned*       wp   = (unsigned*)(ws + wp_o);
    unsigned*       xb   = (unsigned*)(ws + xb_o);

    const int eb = (n_edges + 255) / 256;
    const int nquads = n_nodes * 8;
    const int nout4  = n_nodes * 16;
    const int prep_range = max(max(nquads, nout4), max(n_nodes, WPACK_UINTS));
    const int chunk = (n_nodes + SCAN_NB - 1) / SCAN_NB;

    // 1) fused prep: zero counts + bias-init out + repack weights + convert x
    hipLaunchKernelGGL(prep_kernel, dim3((prep_range + 255) / 256), dim3(256), 0, stream,
                       input, weight, bias, (float*)d_out, xb, wp, cnt,
                       n_nodes, nquads, nout4);
    // 2) counting sort -> CSR records (atomic-free fill)
    hipLaunchKernelGGL(rank_kernel, dim3(eb), dim3(256), 0, stream, ei, cnt, rank, n_edges);
    hipLaunchKernelGGL(scanA_kernel, dim3(SCAN_NB), dim3(256), 0, stream, cnt, par, n_nodes, chunk);
    hipLaunchKernelGGL(scanB_kernel, dim3(1), dim3(SCAN_NB), 0, stream, par, off, n_nodes);
    hipLaunchKernelGGL(scanC_kernel, dim3(SCAN_NB), dim3(256), 0, stream, cnt, par, off, n_nodes, chunk);
    hipLaunchKernelGGL(fill_kernel, dim3(eb), dim3(256), 0, stream, ei, ej, ek, off, rank, recs, n_edges);

    // 3) half-wave-per-edge gather, all-atomic flushes
    hipLaunchKernelGGL(gather_kernel, dim3(512), dim3(1024), 0, stream,
                       xb, recs, wp, (float*)d_out, n_edges);
}